// Round 4
// baseline (174.499 us; speedup 1.0000x reference)
//
#include <hip/hip_runtime.h>
#include <hip/hip_bf16.h>

// ProbabilisticMap: out[b][x][y][t] = scale(b,t) * exp(-0.5 * d^T inv(cov(b,t)) d),
// d = (x,y) - mean(b,t); mean/cov are Bernstein-weighted sums over <=8 control pts.
//
// Round-3 result: PASSED (absmax 4.88e-4 = 1 bf16-ulp comparison floor).
// rocprof: top-5 dispatches are all 512MiB harness poison-fills (~81us each,
// 82% HBM peak) -> our kernel is <81us and dur_us=171.7 is fill-dominated.
// Round-4: float4 nontemporal stores (16B/lane) + ds_read_b128 stat broadcast
// as a differential probe: if dur_us is unchanged, kernel is at the ~21us
// write roofline (134MB / 6.3TB/s) and the rest is harness overhead.
//
// Layouts (C-order), dtype-detected at runtime (worked in R3):
//   cp_means: (K=8, B=128, 2)     fp32 or bf16
//   num_cps : (B=128,)            int32 or int64
//   cp_cov  : (K=8, B=128, 2, 2)  fp32 or bf16
//   out     : (B=128, W=64, H=64, T=64) fp32 -> 134 MB, write-BW-bound
//
// One block per (b,x). Wave 0 computes per-t stats into LDS (block-uniform x
// folded in). Then each thread owns 4 consecutive t at fixed y: stats via
// 5x ds_read_b128 (broadcast, conflict-free), output via float4 nt-stores --
// each wave store covers one contiguous 1 KiB segment.

#define MAP_W 64
#define MAP_H 64
#define T_SIZE 64
#define NUM_CP 8
#define BATCH 128

typedef float v4f __attribute__((ext_vector_type(4)));

__global__ __launch_bounds__(256) void pmap_kernel(
    const void* __restrict__ cp_means_p,
    const void* __restrict__ num_cps_p,
    const void* __restrict__ cp_cov_p,
    float* __restrict__ out)
{
    __shared__ __align__(16) float s_my[T_SIZE];
    __shared__ __align__(16) float s_g11[T_SIZE];
    __shared__ __align__(16) float s_c0[T_SIZE];
    __shared__ __align__(16) float s_c1[T_SIZE];
    __shared__ __align__(16) float s_sc[T_SIZE];

    const int tid = threadIdx.x;
    const int blk = blockIdx.x;        // blk = b*64 + x
    const int b   = blk >> 6;
    const int x   = blk & 63;

    if (tid < T_SIZE) {
        // ---- runtime dtype detection (wave-uniform, deterministic) ----
        const int* ni32 = (const int*)num_cps_p;
        const bool is_i64 = (ni32[1] == 0);              // values 3..8, never 0
        const int  ncp = is_i64 ? (int)((const long long*)num_cps_p)[b] : ni32[b];
        const int  n   = ncp - 1;                        // 2..7

        const __hip_bfloat16* mbv = (const __hip_bfloat16*)cp_means_p;
        const __hip_bfloat16* cbv = (const __hip_bfloat16*)cp_cov_p;
        const float*          mf  = (const float*)cp_means_p;
        const float*          cf  = (const float*)cp_cov_p;
        // means lie in [0,63]; fp32 viewed as bf16 yields out-of-range words
        bool is_f32 = false;
        #pragma unroll
        for (int i = 0; i < 32; ++i) {
            const float v = __bfloat162float(mbv[i]);
            if (!(v >= 0.0f && v <= 64.0f)) is_f32 = true;   // NaN lands here too
        }

        // t = linspace(0,1,64)[tid]
        const float t   = (float)tid * (1.0f / 63.0f);
        const float omt = 1.0f - t;

        // Bernstein-weighted mean & covariance, unrolled over k. Binomial via
        // exact small-int recurrence; (1-t)^(n-k) via unrolled select chain.
        float mx = 0.f, my = 0.f, ca = 0.f, cb = 0.f, cc = 0.f, cd = 0.f;
        float ck = 1.0f, tk = 1.0f;
        #pragma unroll
        for (int k = 0; k < NUM_CP; ++k) {
            const int e = n - k;
            float onk = (e == 0) ? 1.0f : 0.0f;
            float o = 1.0f;
            #pragma unroll
            for (int j = 1; j < NUM_CP; ++j) { o *= omt; if (e == j) onk = o; }
            const float w  = (k <= n) ? ck * tk * onk : 0.0f;
            const float w2 = w * w;
            const int base = k * BATCH + b;
            const float m0 = is_f32 ? mf[base*2+0] : __bfloat162float(mbv[base*2+0]);
            const float m1 = is_f32 ? mf[base*2+1] : __bfloat162float(mbv[base*2+1]);
            const float q0 = is_f32 ? cf[base*4+0] : __bfloat162float(cbv[base*4+0]);
            const float q1 = is_f32 ? cf[base*4+1] : __bfloat162float(cbv[base*4+1]);
            const float q2 = is_f32 ? cf[base*4+2] : __bfloat162float(cbv[base*4+2]);
            const float q3 = is_f32 ? cf[base*4+3] : __bfloat162float(cbv[base*4+3]);
            mx = fmaf(w,  m0, mx);
            my = fmaf(w,  m1, my);
            ca = fmaf(w2, q0, ca);
            cb = fmaf(w2, q1, cb);
            cc = fmaf(w2, q2, cc);
            cd = fmaf(w2, q3, cd);
            ck = ck * (float)(n - k) / (float)(k + 1);
            tk *= t;
        }

        // 2x2 inverse folded with -0.5*log2(e) -> inner loop uses native exp2
        const float det     = fmaf(ca, cd, -(cb * cc));  // > 0 for valid covs
        const float inv_det = 1.0f / det;
        const float HL2E    = 0.72134752044448170368f;   // 0.5 * log2(e)
        const float g00 = -HL2E * cd * inv_det;
        const float gxy =  HL2E * (cb + cc) * inv_det;
        const float g11 = -HL2E * ca * inv_det;
        const float scale = 0.15915494309189535f / sqrtf(det); // 1/(2*pi*sqrt(det))

        // fold block-uniform x into per-t constants
        const float dx = (float)x - mx;
        s_my[tid]  = my;
        s_g11[tid] = g11;
        s_c0[tid]  = g00 * dx * dx;
        s_c1[tid]  = gxy * dx;
        s_sc[tid]  = scale;
    }
    __syncthreads();

    // thread -> (t-group, y-base): 4 consecutive t at fixed y, y strided by 16.
    // Within a wave: lane = 16*(yb&3) + tg -> one contiguous 1 KiB store/wave.
    const int tg = tid & 15;           // t = 4*tg + j
    const int yb = tid >> 4;           // 0..15
    const int t4 = tg << 2;

    // contiguous 16B stat vectors -> ds_read_b128, same-address broadcast
    const v4f my4 = *(const v4f*)&s_my[t4];
    const v4f g4  = *(const v4f*)&s_g11[t4];
    const v4f c04 = *(const v4f*)&s_c0[t4];
    const v4f c14 = *(const v4f*)&s_c1[t4];
    const v4f sc4 = *(const v4f*)&s_sc[t4];

    float* __restrict__ obase = out + ((size_t)blk << 12) + t4;

    #pragma unroll
    for (int i = 0; i < 4; ++i) {
        const int   y  = yb + (i << 4);
        const float fy = (float)y;
        v4f v;
        {   const float dy = fy - my4.x;
            v.x = sc4.x * exp2f(fmaf(dy, fmaf(g4.x, dy, c14.x), c04.x)); }
        {   const float dy = fy - my4.y;
            v.y = sc4.y * exp2f(fmaf(dy, fmaf(g4.y, dy, c14.y), c04.y)); }
        {   const float dy = fy - my4.z;
            v.z = sc4.z * exp2f(fmaf(dy, fmaf(g4.z, dy, c14.z), c04.z)); }
        {   const float dy = fy - my4.w;
            v.w = sc4.w * exp2f(fmaf(dy, fmaf(g4.w, dy, c14.w), c04.w)); }
        // streaming store: 134 MB >> 32 MB L2, skip write-allocate
        __builtin_nontemporal_store(v, (v4f*)(obase + (y << 6)));
    }
}

extern "C" void kernel_launch(void* const* d_in, const int* in_sizes, int n_in,
                              void* d_out, int out_size, void* d_ws, size_t ws_size,
                              hipStream_t stream) {
    pmap_kernel<<<dim3(BATCH * MAP_W), dim3(256), 0, stream>>>(
        d_in[0], d_in[1], d_in[2], (float*)d_out);
}